// Round 1
// baseline (2815.127 us; speedup 1.0000x reference)
//
#include <hip/hip_runtime.h>
#include <math.h>

#define NSAMP 131072
#define DD 12
#define DCC 4
#define LLAYERS 4
#define KK 8
#define HH 64
#define SS 6
#define TOUTW 138
#define BV 3.0f
#define SLP 0.2f
#define BLK 128

__device__ __forceinline__ float leaky(float v) { return v >= 0.0f ? v : SLP * v; }

// out[j] = leaky( sum_i in[i] * W[i*stride + j] + b[j] ),  j < NOUT
// W, b: wave-uniform (scalar-loaded). in: per-thread LDS row. out: registers.
template <int NOUT>
__device__ __forceinline__ void gemv_leaky(const float* __restrict__ W, int stride,
                                           const float* __restrict__ b, int nin,
                                           const float* in, float* out) {
    float acc[NOUT];
#pragma unroll
    for (int j = 0; j < NOUT; ++j) acc[j] = b[j];
#pragma unroll 4
    for (int i = 0; i < nin; ++i) {
        float hi = in[i];
        const float* w = W + i * stride;
#pragma unroll
        for (int j = 0; j < NOUT; ++j) acc[j] = fmaf(hi, w[j], acc[j]);
    }
#pragma unroll
    for (int j = 0; j < NOUT; ++j) out[j] = leaky(acc[j]);
}

// input (nin0 floats) already in buf[0..nin0); leaves final hidden (64) in buf.
__device__ __forceinline__ void mlp_chain(const float* __restrict__ W0, const float* __restrict__ b0,
                                          const float* __restrict__ Wh, const float* __restrict__ bh,
                                          int nin0, float* buf) {
#pragma unroll 1
    for (int step = 0; step < 3; ++step) {
        const float* W = (step == 0) ? W0 : (Wh + (step - 1) * HH * HH);
        const float* b = (step == 0) ? b0 : (bh + (step - 1) * HH);
        int nin = (step == 0) ? nin0 : HH;
        float h[HH];
        gemv_leaky<HH>(W, HH, b, nin, buf, h);
#pragma unroll
        for (int j = 0; j < HH; ++j) buf[j] = h[j];
    }
}

extern "C" __global__ void __launch_bounds__(BLK, 2)
nsflow_main(const float* __restrict__ x_in, const float* __restrict__ xc_in,
            const float* __restrict__ convP, const float* __restrict__ convS,
            const float* __restrict__ convL, const float* __restrict__ convU,
            const float* __restrict__ n1W0, const float* __restrict__ n1b0,
            const float* __restrict__ n1Wh, const float* __restrict__ n1bh,
            const float* __restrict__ n1Wl, const float* __restrict__ n1bl,
            const float* __restrict__ n2W0, const float* __restrict__ n2b0,
            const float* __restrict__ n2Wh, const float* __restrict__ n2bh,
            const float* __restrict__ n2Wl, const float* __restrict__ n2bl,
            const float* __restrict__ c1W0, const float* __restrict__ c1b0,
            const float* __restrict__ c1Wh, const float* __restrict__ c1bh,
            const float* __restrict__ c1Wl, const float* __restrict__ c1bl,
            const float* __restrict__ c2W0, const float* __restrict__ c2b0,
            const float* __restrict__ c2Wh, const float* __restrict__ c2bh,
            const float* __restrict__ c2Wl, const float* __restrict__ c2bl,
            float* __restrict__ out) {
    __shared__ float WcS[LLAYERS][DD][DD];
    __shared__ float ldcS;
    __shared__ float bufAS[BLK * 65];
    __shared__ float bufBS[BLK * 65];

    // ---- per-block setup: W[l] = P (L+I) (U+diag(S)), and conv logdet const ----
    for (int e = threadIdx.x; e < LLAYERS * DD * DD; e += BLK) {
        int l = e / (DD * DD);
        int r = e - l * DD * DD;
        int i = r / DD;
        int j = r - i * DD;
        const float* P = convP + l * DD * DD;
        const float* Lm = convL + l * DD * DD;
        const float* Um = convU + l * DD * DD;
        const float* Sv = convS + l * DD;
        float acc = 0.0f;
        for (int a = 0; a < DD; ++a) {
            float inner = 0.0f;
            for (int bb = 0; bb < DD; ++bb) {
                float m1 = (bb < a) ? Lm[a * DD + bb] : (bb == a ? 1.0f : 0.0f);
                float m2 = (j > bb) ? Um[bb * DD + j] : (j == bb ? Sv[j] : 0.0f);
                inner = fmaf(m1, m2, inner);
            }
            acc = fmaf(P[i * DD + a], inner, acc);
        }
        WcS[l][i][j] = acc;
    }
    if (threadIdx.x == 0) {
        float sacc = 0.0f;
        for (int q = 0; q < LLAYERS * DD; ++q) sacc += __logf(fabsf(convS[q]));
        ldcS = sacc;
    }
    __syncthreads();

    int tid = blockIdx.x * BLK + threadIdx.x;

    float xr[DD];
    float xc[DCC];
    {
        const float4* xv = (const float4*)(x_in + (size_t)tid * DD);
        float4 a0 = xv[0], a1 = xv[1], a2 = xv[2];
        xr[0] = a0.x; xr[1] = a0.y; xr[2] = a0.z; xr[3] = a0.w;
        xr[4] = a1.x; xr[5] = a1.y; xr[6] = a1.z; xr[7] = a1.w;
        xr[8] = a2.x; xr[9] = a2.y; xr[10] = a2.z; xr[11] = a2.w;
        float4 c0 = *(const float4*)(xc_in + (size_t)tid * DCC);
        xc[0] = c0.x; xc[1] = c0.y; xc[2] = c0.z; xc[3] = c0.w;
    }
    float logdet = ldcS;

    float* bufA = bufAS + threadIdx.x * 65;  // net (data) activations
    float* bufB = bufBS + threadIdx.x * 65;  // conditioner activations

#pragma unroll 1
    for (int l = 0; l < LLAYERS; ++l) {
        // x = x @ W[l]
        float xn[DD];
#pragma unroll
        for (int j = 0; j < DD; ++j) xn[j] = 0.0f;
#pragma unroll
        for (int i = 0; i < DD; ++i) {
            float xi = xr[i];
#pragma unroll
            for (int j = 0; j < DD; ++j) xn[j] = fmaf(xi, WcS[l][i][j], xn[j]);
        }
#pragma unroll
        for (int j = 0; j < DD; ++j) xr[j] = xn[j];

#pragma unroll
        for (int half = 0; half < 2; ++half) {
            const float* nW0 = (half ? n2W0 : n1W0) + l * SS * HH;
            const float* nb0 = (half ? n2b0 : n1b0) + l * HH;
            const float* nWh = (half ? n2Wh : n1Wh) + l * 2 * HH * HH;
            const float* nbh = (half ? n2bh : n1bh) + l * 2 * HH;
            const float* nWl = (half ? n2Wl : n1Wl) + l * HH * TOUTW;
            const float* nbl = (half ? n2bl : n1bl) + l * TOUTW;
            const float* cW0 = (half ? c2W0 : c1W0) + l * DCC * HH;
            const float* cb0 = (half ? c2b0 : c1b0) + l * HH;
            const float* cWh = (half ? c2Wh : c1Wh) + l * 2 * HH * HH;
            const float* cbh = (half ? c2bh : c1bh) + l * 2 * HH;
            const float* cWl = (half ? c2Wl : c1Wl) + l * HH * TOUTW;
            const float* cbl = (half ? c2bl : c1bl) + l * TOUTW;

            // conditioner MLP hidden chain (input x_cond)
#pragma unroll
            for (int i = 0; i < DCC; ++i) bufB[i] = xc[i];
            mlp_chain(cW0, cb0, cWh, cbh, DCC, bufB);

            // data MLP hidden chain (input = untouched half)
            if (half == 0) {
#pragma unroll
                for (int i = 0; i < SS; ++i) bufA[i] = xr[i];
            } else {
#pragma unroll
                for (int i = 0; i < SS; ++i) bufA[i] = xr[SS + i];
            }
            mlp_chain(nW0, nb0, nWh, nbh, SS, bufA);

            // per spline dim: 23 outputs from each net, product, RQS transform
#pragma unroll
            for (int dd = 0; dd < SS; ++dd) {
                float tnc[23], tnet[23];
                gemv_leaky<23>(cWl + dd * 23, TOUTW, cbl + dd * 23, HH, bufB, tnc);
                gemv_leaky<23>(nWl + dd * 23, TOUTW, nbl + dd * 23, HH, bufA, tnet);
                float th[23];
#pragma unroll
                for (int j = 0; j < 23; ++j) th[j] = tnc[j] * tnet[j];

                // widths softmax * 2B
                float mw = th[0];
#pragma unroll
                for (int j = 1; j < KK; ++j) mw = fmaxf(mw, th[j]);
                float ew[KK];
                float swsum = 0.0f;
#pragma unroll
                for (int j = 0; j < KK; ++j) { ew[j] = __expf(th[j] - mw); swsum += ew[j]; }
                float iw_ = 6.0f / swsum;
                // heights softmax * 2B
                float mh = th[KK];
#pragma unroll
                for (int j = 1; j < KK; ++j) mh = fmaxf(mh, th[KK + j]);
                float eh[KK];
                float shsum = 0.0f;
#pragma unroll
                for (int j = 0; j < KK; ++j) { eh[j] = __expf(th[KK + j] - mh); shsum += eh[j]; }
                float ih_ = 6.0f / shsum;
                // derivs: softplus, padded with 1.0 at both ends
                float dv[KK + 1];
                dv[0] = 1.0f;
                dv[KK] = 1.0f;
#pragma unroll
                for (int j = 0; j < KK - 1; ++j) {
                    float v = th[2 * KK + j];
                    float z = __expf(-fabsf(v));
                    dv[j + 1] = fmaxf(v, 0.0f) + __logf(1.0f + z);
                }

                float X = (half == 0) ? xr[SS + dd] : xr[dd];
                float Xc = fminf(fmaxf(X, -BV), BV);

                // bin scan: select last bin j with Xc >= left_edge[j]
                float cx = -BV, cy = -BV;
                float xk = -BV, xk1 = BV, yk = -BV, yk1 = BV, dk = 1.0f, dk1 = 1.0f;
#pragma unroll
                for (int j = 0; j < KK; ++j) {
                    float nx = (j == KK - 1) ? (BV + 1e-6f) : (cx + ew[j] * iw_);
                    float ny = (j == KK - 1) ? BV : (cy + eh[j] * ih_);
                    bool sel = (j == 0) || (Xc >= cx);
                    if (sel) { xk = cx; xk1 = nx; yk = cy; yk1 = ny; dk = dv[j]; dk1 = dv[j + 1]; }
                    cx = nx;
                    cy = ny;
                }

                float idx_ = 1.0f / (xk1 - xk);
                float s_ = (yk1 - yk) * idx_;
                float xi = (Xc - xk) * idx_;
                float om = 1.0f - xi;
                float xo = xi * om;
                float den = s_ + (dk1 + dk - 2.0f * s_) * xo;
                float Y = yk + (yk1 - yk) * (s_ * xi * xi + dk * xo) / den;
                float dydx = s_ * s_ * (dk1 * xi * xi + 2.0f * s_ * xo + dk * om * om) / (den * den);
                bool inside = (X <= BV) && (X >= -BV);
                float Yo = inside ? Y : X;
                logdet += inside ? __logf(dydx) : 0.0f;
                if (half == 0) xr[SS + dd] = Yo; else xr[dd] = Yo;
            }
        }
    }

    float pr = 0.0f;
#pragma unroll
    for (int j = 0; j < DD; ++j) pr = fmaf(-0.5f * xr[j], xr[j], pr);
    pr -= DD * 0.91893853320467274f;

    float4* ov = (float4*)(out + (size_t)tid * DD);
    ov[0] = make_float4(xr[0], xr[1], xr[2], xr[3]);
    ov[1] = make_float4(xr[4], xr[5], xr[6], xr[7]);
    ov[2] = make_float4(xr[8], xr[9], xr[10], xr[11]);
    out[(size_t)NSAMP * DD + tid] = logdet;
    out[(size_t)NSAMP * DD + NSAMP + tid] = pr;
}

extern "C" void kernel_launch(void* const* d_in, const int* in_sizes, int n_in,
                              void* d_out, int out_size, void* d_ws, size_t ws_size,
                              hipStream_t stream) {
    (void)in_sizes; (void)n_in; (void)out_size; (void)d_ws; (void)ws_size;
    const float* a[30];
    for (int i = 0; i < 30; ++i) a[i] = (const float*)d_in[i];
    dim3 grid(NSAMP / BLK), block(BLK);
    hipLaunchKernelGGL(nsflow_main, grid, block, 0, stream,
                       a[0], a[1], a[2], a[3], a[4], a[5],
                       a[6], a[7], a[8], a[9], a[10], a[11],
                       a[12], a[13], a[14], a[15], a[16], a[17],
                       a[18], a[19], a[20], a[21], a[22], a[23],
                       a[24], a[25], a[26], a[27], a[28], a[29],
                       (float*)d_out);
}

// Round 2
// 1863.958 us; speedup vs baseline: 1.5103x; 1.5103x over previous
//
#include <hip/hip_runtime.h>
#include <math.h>

#define NSAMP 131072
#define DD 12
#define DCC 4
#define LLAYERS 4
#define KK 8
#define HH 64
#define SS 6
#define TOUTW 138
#define BV 3.0f
#define SLP 0.2f
#define BLK 128
#define ROWDW 36  // dwords per LDS activation row: 64 bf16 = 32 dw + pad, 144 B (16B aligned)

__device__ __forceinline__ float leaky(float v) { return v >= 0.0f ? v : SLP * v; }

__device__ __forceinline__ uint f2bf(float f) {
    uint u = __float_as_uint(f);
    return (u + 0x7FFFu + ((u >> 16) & 1u)) >> 16;  // RNE
}
__device__ __forceinline__ float bflo(uint q) { return __uint_as_float(q << 16); }
__device__ __forceinline__ float bfhi(uint q) { return __uint_as_float(q & 0xFFFF0000u); }

// ---- gemv with register-resident input (first layers), fully unrolled ----
template <int NIN, int NOUT>
__device__ __forceinline__ void gemv_reg(const float* __restrict__ W, int stride,
                                         const float* __restrict__ b,
                                         const float* in, float* out) {
    float acc[NOUT];
#pragma unroll
    for (int j = 0; j < NOUT; ++j) acc[j] = b[j];
#pragma unroll
    for (int i = 0; i < NIN; ++i) {
        float hi = in[i];
        const float* w = W + i * stride;
#pragma unroll
        for (int j = 0; j < NOUT; ++j) acc[j] = fmaf(hi, w[j], acc[j]);
    }
#pragma unroll
    for (int j = 0; j < NOUT; ++j) out[j] = leaky(acc[j]);
}

// ---- gemv reading bf16 activations from a per-thread LDS row in 8-element bursts ----
template <int NOUT>
__device__ __forceinline__ void gemv_lds(const float* __restrict__ W, int stride,
                                         const float* __restrict__ b, int nin8,
                                         const uint* row, float* out) {
    float acc[NOUT];
#pragma unroll
    for (int j = 0; j < NOUT; ++j) acc[j] = b[j];
#pragma unroll 2
    for (int ib = 0; ib < nin8; ++ib) {
        uint4 q = *(const uint4*)(row + ib * 4);
        float f0 = bflo(q.x), f1 = bfhi(q.x), f2 = bflo(q.y), f3 = bfhi(q.y);
        float f4 = bflo(q.z), f5 = bfhi(q.z), f6 = bflo(q.w), f7 = bfhi(q.w);
        const float* w = W + ib * 8 * stride;
#pragma unroll
        for (int j = 0; j < NOUT; ++j) acc[j] = fmaf(f0, w[0 * stride + j], acc[j]);
#pragma unroll
        for (int j = 0; j < NOUT; ++j) acc[j] = fmaf(f1, w[1 * stride + j], acc[j]);
#pragma unroll
        for (int j = 0; j < NOUT; ++j) acc[j] = fmaf(f2, w[2 * stride + j], acc[j]);
#pragma unroll
        for (int j = 0; j < NOUT; ++j) acc[j] = fmaf(f3, w[3 * stride + j], acc[j]);
#pragma unroll
        for (int j = 0; j < NOUT; ++j) acc[j] = fmaf(f4, w[4 * stride + j], acc[j]);
#pragma unroll
        for (int j = 0; j < NOUT; ++j) acc[j] = fmaf(f5, w[5 * stride + j], acc[j]);
#pragma unroll
        for (int j = 0; j < NOUT; ++j) acc[j] = fmaf(f6, w[6 * stride + j], acc[j]);
#pragma unroll
        for (int j = 0; j < NOUT; ++j) acc[j] = fmaf(f7, w[7 * stride + j], acc[j]);
    }
#pragma unroll
    for (int j = 0; j < NOUT; ++j) out[j] = leaky(acc[j]);
}

// pack 64 fp32 -> 32 dwords of bf16 pairs, 8 x ds_write_b128
__device__ __forceinline__ void store_row64(uint* row, const float* h) {
#pragma unroll
    for (int d = 0; d < 32; d += 4) {
        uint4 q;
        q.x = f2bf(h[2 * d + 0]) | (f2bf(h[2 * d + 1]) << 16);
        q.y = f2bf(h[2 * d + 2]) | (f2bf(h[2 * d + 3]) << 16);
        q.z = f2bf(h[2 * d + 4]) | (f2bf(h[2 * d + 5]) << 16);
        q.w = f2bf(h[2 * d + 6]) | (f2bf(h[2 * d + 7]) << 16);
        *(uint4*)(row + d) = q;
    }
}

// full MLP hidden chain: reg input -> final 64-wide hidden left as bf16 in LDS row
template <int NIN>
__device__ __forceinline__ void run_chain(const float* __restrict__ W0, const float* __restrict__ b0,
                                          const float* __restrict__ Wh, const float* __restrict__ bh,
                                          const float* in, uint* row) {
    float h[HH];
    gemv_reg<NIN, HH>(W0, HH, b0, in, h);
    store_row64(row, h);
#pragma unroll 1
    for (int step = 0; step < 2; ++step) {
        gemv_lds<HH>(Wh + step * HH * HH, HH, bh + step * HH, HH / 8, row, h);
        store_row64(row, h);
    }
}

extern "C" __global__ void __launch_bounds__(BLK, 2)
nsflow_main(const float* __restrict__ x_in, const float* __restrict__ xc_in,
            const float* __restrict__ convP, const float* __restrict__ convS,
            const float* __restrict__ convL, const float* __restrict__ convU,
            const float* __restrict__ n1W0, const float* __restrict__ n1b0,
            const float* __restrict__ n1Wh, const float* __restrict__ n1bh,
            const float* __restrict__ n1Wl, const float* __restrict__ n1bl,
            const float* __restrict__ n2W0, const float* __restrict__ n2b0,
            const float* __restrict__ n2Wh, const float* __restrict__ n2bh,
            const float* __restrict__ n2Wl, const float* __restrict__ n2bl,
            const float* __restrict__ c1W0, const float* __restrict__ c1b0,
            const float* __restrict__ c1Wh, const float* __restrict__ c1bh,
            const float* __restrict__ c1Wl, const float* __restrict__ c1bl,
            const float* __restrict__ c2W0, const float* __restrict__ c2b0,
            const float* __restrict__ c2Wh, const float* __restrict__ c2bh,
            const float* __restrict__ c2Wl, const float* __restrict__ c2bl,
            float* __restrict__ out) {
    __shared__ float WcS[LLAYERS][DD][DD];
    __shared__ float ldcS;
    __shared__ uint bufAS[BLK * ROWDW];
    __shared__ uint bufBS[BLK * ROWDW];

    // ---- per-block setup: W[l] = P (L+I) (U+diag(S)), and conv logdet const ----
    for (int e = threadIdx.x; e < LLAYERS * DD * DD; e += BLK) {
        int l = e / (DD * DD);
        int r = e - l * DD * DD;
        int i = r / DD;
        int j = r - i * DD;
        const float* P = convP + l * DD * DD;
        const float* Lm = convL + l * DD * DD;
        const float* Um = convU + l * DD * DD;
        const float* Sv = convS + l * DD;
        float acc = 0.0f;
        for (int a = 0; a < DD; ++a) {
            float inner = 0.0f;
            for (int bb = 0; bb < DD; ++bb) {
                float m1 = (bb < a) ? Lm[a * DD + bb] : (bb == a ? 1.0f : 0.0f);
                float m2 = (j > bb) ? Um[bb * DD + j] : (j == bb ? Sv[j] : 0.0f);
                inner = fmaf(m1, m2, inner);
            }
            acc = fmaf(P[i * DD + a], inner, acc);
        }
        WcS[l][i][j] = acc;
    }
    if (threadIdx.x == 0) {
        float sacc = 0.0f;
        for (int q = 0; q < LLAYERS * DD; ++q) sacc += __logf(fabsf(convS[q]));
        ldcS = sacc;
    }
    __syncthreads();

    int tid = blockIdx.x * BLK + threadIdx.x;

    float xr[DD];
    float xc[DCC];
    {
        const float4* xv = (const float4*)(x_in + (size_t)tid * DD);
        float4 a0 = xv[0], a1 = xv[1], a2 = xv[2];
        xr[0] = a0.x; xr[1] = a0.y; xr[2] = a0.z; xr[3] = a0.w;
        xr[4] = a1.x; xr[5] = a1.y; xr[6] = a1.z; xr[7] = a1.w;
        xr[8] = a2.x; xr[9] = a2.y; xr[10] = a2.z; xr[11] = a2.w;
        float4 c0 = *(const float4*)(xc_in + (size_t)tid * DCC);
        xc[0] = c0.x; xc[1] = c0.y; xc[2] = c0.z; xc[3] = c0.w;
    }
    float logdet = ldcS;

    uint* rowA = bufAS + threadIdx.x * ROWDW;  // data-net activations (bf16 pairs)
    uint* rowB = bufBS + threadIdx.x * ROWDW;  // conditioner activations

#pragma unroll 1
    for (int l = 0; l < LLAYERS; ++l) {
        // x = x @ W[l]
        float xn[DD];
#pragma unroll
        for (int j = 0; j < DD; ++j) xn[j] = 0.0f;
#pragma unroll
        for (int i = 0; i < DD; ++i) {
            float xi = xr[i];
#pragma unroll
            for (int j = 0; j < DD; ++j) xn[j] = fmaf(xi, WcS[l][i][j], xn[j]);
        }
#pragma unroll
        for (int j = 0; j < DD; ++j) xr[j] = xn[j];

#pragma unroll 1
        for (int half = 0; half < 2; ++half) {
            const float* nW0 = (half ? n2W0 : n1W0) + l * SS * HH;
            const float* nb0 = (half ? n2b0 : n1b0) + l * HH;
            const float* nWh = (half ? n2Wh : n1Wh) + l * 2 * HH * HH;
            const float* nbh = (half ? n2bh : n1bh) + l * 2 * HH;
            const float* nWl = (half ? n2Wl : n1Wl) + l * HH * TOUTW;
            const float* nbl = (half ? n2bl : n1bl) + l * TOUTW;
            const float* cW0 = (half ? c2W0 : c1W0) + l * DCC * HH;
            const float* cb0 = (half ? c2b0 : c1b0) + l * HH;
            const float* cWh = (half ? c2Wh : c1Wh) + l * 2 * HH * HH;
            const float* cbh = (half ? c2bh : c1bh) + l * 2 * HH;
            const float* cWl = (half ? c2Wl : c1Wl) + l * HH * TOUTW;
            const float* cbl = (half ? c2bl : c1bl) + l * TOUTW;

            // conditioner MLP chain (input x_cond, registers)
            run_chain<DCC>(cW0, cb0, cWh, cbh, xc, rowB);
            // data MLP chain (input = untouched half, registers)
            float din[SS];
#pragma unroll
            for (int i = 0; i < SS; ++i) din[i] = half ? xr[SS + i] : xr[i];
            run_chain<SS>(nW0, nb0, nWh, nbh, din, rowA);

            // per spline dim: 23 outputs from each net, product, RQS transform
#pragma unroll 1
            for (int dd = 0; dd < SS; ++dd) {
                float tnc[23], tnet[23];
                gemv_lds<23>(cWl + dd * 23, TOUTW, cbl + dd * 23, HH / 8, rowB, tnc);
                gemv_lds<23>(nWl + dd * 23, TOUTW, nbl + dd * 23, HH / 8, rowA, tnet);
                float th[23];
#pragma unroll
                for (int j = 0; j < 23; ++j) th[j] = tnc[j] * tnet[j];

                // widths softmax * 2B
                float mw = th[0];
#pragma unroll
                for (int j = 1; j < KK; ++j) mw = fmaxf(mw, th[j]);
                float ew[KK];
                float swsum = 0.0f;
#pragma unroll
                for (int j = 0; j < KK; ++j) { ew[j] = __expf(th[j] - mw); swsum += ew[j]; }
                float iw_ = 6.0f / swsum;
                // heights softmax * 2B
                float mh = th[KK];
#pragma unroll
                for (int j = 1; j < KK; ++j) mh = fmaxf(mh, th[KK + j]);
                float eh[KK];
                float shsum = 0.0f;
#pragma unroll
                for (int j = 0; j < KK; ++j) { eh[j] = __expf(th[KK + j] - mh); shsum += eh[j]; }
                float ih_ = 6.0f / shsum;
                // derivs: softplus, padded with 1.0 at both ends
                float dv[KK + 1];
                dv[0] = 1.0f;
                dv[KK] = 1.0f;
#pragma unroll
                for (int j = 0; j < KK - 1; ++j) {
                    float v = th[2 * KK + j];
                    float z = __expf(-fabsf(v));
                    dv[j + 1] = fmaxf(v, 0.0f) + __logf(1.0f + z);
                }

                float X = (half == 0) ? xr[SS + dd] : xr[dd];
                float Xc = fminf(fmaxf(X, -BV), BV);

                // bin scan: select last bin j with Xc >= left_edge[j]
                float cx = -BV, cy = -BV;
                float xk = -BV, xk1 = BV, yk = -BV, yk1 = BV, dk = 1.0f, dk1 = 1.0f;
#pragma unroll
                for (int j = 0; j < KK; ++j) {
                    float nx = (j == KK - 1) ? (BV + 1e-6f) : (cx + ew[j] * iw_);
                    float ny = (j == KK - 1) ? BV : (cy + eh[j] * ih_);
                    bool sel = (j == 0) || (Xc >= cx);
                    if (sel) { xk = cx; xk1 = nx; yk = cy; yk1 = ny; dk = dv[j]; dk1 = dv[j + 1]; }
                    cx = nx;
                    cy = ny;
                }

                float idx_ = 1.0f / (xk1 - xk);
                float s_ = (yk1 - yk) * idx_;
                float xi = (Xc - xk) * idx_;
                float om = 1.0f - xi;
                float xo = xi * om;
                float den = s_ + (dk1 + dk - 2.0f * s_) * xo;
                float Y = yk + (yk1 - yk) * (s_ * xi * xi + dk * xo) / den;
                float dydx = s_ * s_ * (dk1 * xi * xi + 2.0f * s_ * xo + dk * om * om) / (den * den);
                bool inside = (X <= BV) && (X >= -BV);
                float Yo = inside ? Y : X;
                logdet += inside ? __logf(dydx) : 0.0f;
                if (half == 0) xr[SS + dd] = Yo; else xr[dd] = Yo;
            }
        }
    }

    float pr = 0.0f;
#pragma unroll
    for (int j = 0; j < DD; ++j) pr = fmaf(-0.5f * xr[j], xr[j], pr);
    pr -= DD * 0.91893853320467274f;

    float4* ov = (float4*)(out + (size_t)tid * DD);
    ov[0] = make_float4(xr[0], xr[1], xr[2], xr[3]);
    ov[1] = make_float4(xr[4], xr[5], xr[6], xr[7]);
    ov[2] = make_float4(xr[8], xr[9], xr[10], xr[11]);
    out[(size_t)NSAMP * DD + tid] = logdet;
    out[(size_t)NSAMP * DD + NSAMP + tid] = pr;
}

extern "C" void kernel_launch(void* const* d_in, const int* in_sizes, int n_in,
                              void* d_out, int out_size, void* d_ws, size_t ws_size,
                              hipStream_t stream) {
    (void)in_sizes; (void)n_in; (void)out_size; (void)d_ws; (void)ws_size;
    const float* a[30];
    for (int i = 0; i < 30; ++i) a[i] = (const float*)d_in[i];
    dim3 grid(NSAMP / BLK), block(BLK);
    hipLaunchKernelGGL(nsflow_main, grid, block, 0, stream,
                       a[0], a[1], a[2], a[3], a[4], a[5],
                       a[6], a[7], a[8], a[9], a[10], a[11],
                       a[12], a[13], a[14], a[15], a[16], a[17],
                       a[18], a[19], a[20], a[21], a[22], a[23],
                       a[24], a[25], a[26], a[27], a[28], a[29],
                       (float*)d_out);
}

// Round 3
// 626.135 us; speedup vs baseline: 4.4960x; 2.9769x over previous
//
#include <hip/hip_runtime.h>
#include <math.h>

typedef _Float16 f16;
typedef _Float16 f16x8 __attribute__((ext_vector_type(8)));
typedef float f32x4 __attribute__((ext_vector_type(4)));
typedef unsigned int uint32;
typedef unsigned short ushort16;

#define NSAMP 131072
#define DD 12
#define LLAYERS 4
#define KK 8
#define BV 3.0f
#define SLP 0.2f
#define BLK 256
#define NLW 17920   // f16 elems per (net,layer) in ws: 512 (W0) + 8192 (Wh) + 9216 (Wl)
#define WS_WH 512
#define WS_WL 8704

__device__ __forceinline__ float leaky(float v){ return v >= 0.f ? v : SLP * v; }

__device__ __forceinline__ uint32 packh(float a, float b){
    union { f16 h; ushort16 u; } x, y;
    x.h = (f16)a; y.h = (f16)b;
    return (uint32)x.u | ((uint32)y.u << 16);
}
__device__ __forceinline__ float unpl(uint32 v){ union { ushort16 u; f16 h; } c; c.u = (ushort16)v; return (float)c.h; }
__device__ __forceinline__ float unph(uint32 v){ union { ushort16 u; f16 h; } c; c.u = (ushort16)(v >> 16); return (float)c.h; }

__device__ __forceinline__ f32x4 MF(f16x8 a, f16x8 b, f32x4 c){
    return __builtin_amdgcn_mfma_f32_16x16x32_f16(a, b, c, 0, 0, 0);
}

// act tile: per-wave [64 samples][64 feats] f16, row=128B, XOR-swizzled by ((s&7)<<4)
__device__ __forceinline__ const f16x8* actRd(const f16* actW, int s, int fb){
    return (const f16x8*)((const char*)actW + s * 128 + (fb ^ ((s & 7) << 4)));
}
__device__ __forceinline__ uint2* actWr(f16* actW, int s, int fb){
    return (uint2*)((char*)actW + s * 128 + (fb ^ ((s & 7) << 4)));
}

// ---------------- prep kernel: split weights into fp16 hi/lo, fragment-ordered ----------------
extern "C" __global__ void nsflow_prep(const float* __restrict__ n1W0, const float* __restrict__ n1Wh, const float* __restrict__ n1Wl,
                                       const float* __restrict__ n2W0, const float* __restrict__ n2Wh, const float* __restrict__ n2Wl,
                                       const float* __restrict__ c1W0, const float* __restrict__ c1Wh, const float* __restrict__ c1Wl,
                                       const float* __restrict__ c2W0, const float* __restrict__ c2Wh, const float* __restrict__ c2Wl,
                                       f16* __restrict__ ws_hi, f16* __restrict__ ws_lo){
    int NL = blockIdx.y;                     // l*4 + net, net: 0=c1 1=n1 2=c2 3=n2
    int off = blockIdx.x * 256 + threadIdx.x; // 0..17919
    int layer = NL >> 2, net = NL & 3;
    const float *W0, *Wh, *Wl; int nin;
    if (net == 0){ W0 = c1W0; Wh = c1Wh; Wl = c1Wl; nin = 4; }
    else if (net == 1){ W0 = n1W0; Wh = n1Wh; Wl = n1Wl; nin = 6; }
    else if (net == 2){ W0 = c2W0; Wh = c2Wh; Wl = c2Wl; nin = 4; }
    else { W0 = n2W0; Wh = n2Wh; Wl = n2Wl; nin = 6; }

    float w = 0.f;
    if (off < 512){                          // W0^T frags: [mt(4)][16 lanes][8 j]
        int mt = off >> 7, r = off & 127, ln = r >> 3, j = r & 7;
        int row = mt * 16 + ln;              // row = f_out
        if (j < nin) w = W0[(layer * nin + j) * 64 + row];
    } else if (off < 8704){                  // Wh^T frags: [h(2)][mt*2+ks (8)][64 lanes][8 j]
        int o = off - 512; int h = o >> 12; o &= 4095;
        int t = o >> 9, ln = (o >> 3) & 63, j = o & 7;
        int mt = t >> 1, ks = t & 1;
        int k = ks * 32 + (ln >> 4) * 8 + j, row = mt * 16 + (ln & 15);
        w = Wh[((layer * 2 + h) * 64 + k) * 64 + row];
    } else {                                 // Wl^T frags: [mt*2+ks (18)][64 lanes][8 j]
        int o = off - 8704;
        int t = o >> 9, ln = (o >> 3) & 63, j = o & 7;
        int mt = t >> 1, ks = t & 1;
        int k = ks * 32 + (ln >> 4) * 8 + j, row = mt * 16 + (ln & 15);
        if (row < 138) w = Wl[(layer * 64 + k) * 138 + row];
    }
    f16 hi = (f16)w;
    f16 lo = (f16)(w - (float)hi);
    ws_hi[NL * NLW + off] = hi;
    ws_lo[NL * NLW + off] = lo;
}

// ---------------- GEMM helpers (per wave, in-place act tile) ----------------
// first layer: B from staging rows (K padded to 32, only g==0 lanes carry data via A)
__device__ __forceinline__ void gemmL0(const f16* __restrict__ ah, const f16* __restrict__ al,
                                       const float* __restrict__ bias,
                                       const f16* src, int strideE, int offE,
                                       f16* actW, int lane, int widS){
    int l15 = lane & 15, g = lane >> 4;
    f16x8 Z;
#pragma unroll
    for (int j = 0; j < 8; ++j) Z[j] = (f16)0.f;
    f16x8 Bf[4];
#pragma unroll
    for (int nt = 0; nt < 4; ++nt)
        Bf[nt] = *(const f16x8*)(src + (widS + nt * 16 + l15) * strideE + offE);
    float blv[4][4];
#pragma unroll
    for (int mt = 0; mt < 4; ++mt)
#pragma unroll
        for (int i = 0; i < 4; ++i) blv[mt][i] = bias[mt * 16 + g * 4 + i];
    bool g0 = (g == 0);
#pragma unroll
    for (int mt = 0; mt < 4; ++mt){
        f16x8 Ah = g0 ? *(const f16x8*)(ah + (mt * 16 + l15) * 8) : Z;
        f16x8 Al = g0 ? *(const f16x8*)(al + (mt * 16 + l15) * 8) : Z;
#pragma unroll
        for (int nt = 0; nt < 4; ++nt){
            f32x4 acc = {0.f, 0.f, 0.f, 0.f};
            acc = MF(Ah, Bf[nt], acc);
            acc = MF(Al, Bf[nt], acc);
            float h0 = leaky(acc[0] + blv[mt][0]);
            float h1 = leaky(acc[1] + blv[mt][1]);
            float h2 = leaky(acc[2] + blv[mt][2]);
            float h3 = leaky(acc[3] + blv[mt][3]);
            uint2 v = { packh(h0, h1), packh(h2, h3) };
            *actWr(actW, nt * 16 + l15, mt * 32 + g * 8) = v;
        }
    }
}

// hidden 64->64 layer, in place (all B fragments pre-loaded before first write)
__device__ __forceinline__ void gemm64(const f16* __restrict__ ah, const f16* __restrict__ al,
                                       const float* __restrict__ bias,
                                       f16* actW, int lane){
    int l15 = lane & 15, g = lane >> 4;
    f16x8 Bf[4][2];
#pragma unroll
    for (int nt = 0; nt < 4; ++nt)
#pragma unroll
        for (int ks = 0; ks < 2; ++ks)
            Bf[nt][ks] = *actRd(actW, nt * 16 + l15, ks * 64 + g * 16);
    float blv[4][4];
#pragma unroll
    for (int mt = 0; mt < 4; ++mt)
#pragma unroll
        for (int i = 0; i < 4; ++i) blv[mt][i] = bias[mt * 16 + g * 4 + i];
#pragma unroll
    for (int mt = 0; mt < 4; ++mt){
        f16x8 Ah0 = *(const f16x8*)(ah + ((mt * 2 + 0) * 64 + lane) * 8);
        f16x8 Ah1 = *(const f16x8*)(ah + ((mt * 2 + 1) * 64 + lane) * 8);
        f16x8 Al0 = *(const f16x8*)(al + ((mt * 2 + 0) * 64 + lane) * 8);
        f16x8 Al1 = *(const f16x8*)(al + ((mt * 2 + 1) * 64 + lane) * 8);
#pragma unroll
        for (int nt = 0; nt < 4; ++nt){
            f32x4 acc = {0.f, 0.f, 0.f, 0.f};
            acc = MF(Ah0, Bf[nt][0], acc);
            acc = MF(Al0, Bf[nt][0], acc);
            acc = MF(Ah1, Bf[nt][1], acc);
            acc = MF(Al1, Bf[nt][1], acc);
            float h0 = leaky(acc[0] + blv[mt][0]);
            float h1 = leaky(acc[1] + blv[mt][1]);
            float h2 = leaky(acc[2] + blv[mt][2]);
            float h3 = leaky(acc[3] + blv[mt][3]);
            uint2 v = { packh(h0, h1), packh(h2, h3) };
            *actWr(actW, nt * 16 + l15, mt * 32 + g * 8) = v;
        }
    }
}

// final layer (conditioner): 64 -> 144(pad of 138), result kept packed in regs
__device__ __forceinline__ void gemmFinC(const f16* __restrict__ ah, const f16* __restrict__ al,
                                         const float* __restrict__ bias,
                                         const f16* actW, int lane, uint2 (&tcp)[9][4]){
    int l15 = lane & 15, g = lane >> 4;
    float blv[9][4];
#pragma unroll
    for (int mt = 0; mt < 9; ++mt)
#pragma unroll
        for (int i = 0; i < 4; ++i){
            int f = mt * 16 + g * 4 + i;
            blv[mt][i] = bias[f < 138 ? f : 137];
        }
#pragma unroll
    for (int nt = 0; nt < 4; ++nt){
        f16x8 B0 = *actRd(actW, nt * 16 + l15, g * 16);
        f16x8 B1 = *actRd(actW, nt * 16 + l15, 64 + g * 16);
#pragma unroll
        for (int mt = 0; mt < 9; ++mt){
            f16x8 Ah0 = *(const f16x8*)(ah + ((mt * 2 + 0) * 64 + lane) * 8);
            f16x8 Ah1 = *(const f16x8*)(ah + ((mt * 2 + 1) * 64 + lane) * 8);
            f16x8 Al0 = *(const f16x8*)(al + ((mt * 2 + 0) * 64 + lane) * 8);
            f16x8 Al1 = *(const f16x8*)(al + ((mt * 2 + 1) * 64 + lane) * 8);
            f32x4 acc = {0.f, 0.f, 0.f, 0.f};
            acc = MF(Ah0, B0, acc);
            acc = MF(Al0, B0, acc);
            acc = MF(Ah1, B1, acc);
            acc = MF(Al1, B1, acc);
            float h0 = leaky(acc[0] + blv[mt][0]);
            float h1 = leaky(acc[1] + blv[mt][1]);
            float h2 = leaky(acc[2] + blv[mt][2]);
            float h3 = leaky(acc[3] + blv[mt][3]);
            tcp[mt][nt].x = packh(h0, h1);
            tcp[mt][nt].y = packh(h2, h3);
        }
    }
}

// spline for one chunk of 16 samples (th rows in thW, dims padded to 24 f16)
__device__ __forceinline__ void spline_chunk(const f16* thW, f16* xst, float* ldb,
                                             int sbase, int half, int lane){
#pragma unroll 1
    for (int pass = 0; pass < 2; ++pass){
        if (pass == 1 && lane >= 32) break;
        int dd = pass * 4 + (lane >> 4);
        int s16 = lane & 15;

        const f16* tr = thW + s16 * 144 + dd * 24;
        f16x8 t0 = *(const f16x8*)(tr);
        f16x8 t1 = *(const f16x8*)(tr + 8);
        f16x8 t2 = *(const f16x8*)(tr + 16);
        float th[23];
#pragma unroll
        for (int j = 0; j < 8; ++j) th[j] = (float)t0[j];
#pragma unroll
        for (int j = 0; j < 8; ++j) th[8 + j] = (float)t1[j];
#pragma unroll
        for (int j = 0; j < 7; ++j) th[16 + j] = (float)t2[j];

        // widths softmax * 2B
        float mw = th[0];
#pragma unroll
        for (int j = 1; j < KK; ++j) mw = fmaxf(mw, th[j]);
        float ew[KK]; float swsum = 0.f;
#pragma unroll
        for (int j = 0; j < KK; ++j){ ew[j] = __expf(th[j] - mw); swsum += ew[j]; }
        float iw_ = 6.0f / swsum;
        // heights softmax * 2B
        float mh = th[KK];
#pragma unroll
        for (int j = 1; j < KK; ++j) mh = fmaxf(mh, th[KK + j]);
        float eh[KK]; float shsum = 0.f;
#pragma unroll
        for (int j = 0; j < KK; ++j){ eh[j] = __expf(th[KK + j] - mh); shsum += eh[j]; }
        float ih_ = 6.0f / shsum;
        // derivs softplus, padded 1.0 ends
        float dv[KK + 1];
        dv[0] = 1.0f; dv[KK] = 1.0f;
#pragma unroll
        for (int j = 0; j < KK - 1; ++j){
            float v = th[2 * KK + j];
            float z = __expf(-fabsf(v));
            dv[j + 1] = fmaxf(v, 0.f) + __logf(1.0f + z);
        }

        int sidx = sbase + s16;
        int slot = half ? dd : 8 + dd;
        float X = (float)xst[sidx * 16 + slot];
        float Xc = fminf(fmaxf(X, -BV), BV);

        float cx = -BV, cy = -BV;
        float xk = -BV, xk1 = BV, yk = -BV, yk1 = BV, dk = 1.0f, dk1 = 1.0f;
#pragma unroll
        for (int j = 0; j < KK; ++j){
            float nx = (j == KK - 1) ? (BV + 1e-6f) : (cx + ew[j] * iw_);
            float ny = (j == KK - 1) ? BV : (cy + eh[j] * ih_);
            bool sel = (j == 0) || (Xc >= cx);
            if (sel){ xk = cx; xk1 = nx; yk = cy; yk1 = ny; dk = dv[j]; dk1 = dv[j + 1]; }
            cx = nx; cy = ny;
        }
        float idx_ = 1.0f / (xk1 - xk);
        float s_ = (yk1 - yk) * idx_;
        float xi = (Xc - xk) * idx_;
        float om = 1.0f - xi;
        float xo = xi * om;
        float den = s_ + (dk1 + dk - 2.0f * s_) * xo;
        float Y = yk + (yk1 - yk) * (s_ * xi * xi + dk * xo) / den;
        float dydx = s_ * s_ * (dk1 * xi * xi + 2.0f * s_ * xo + dk * om * om) / (den * den);
        bool inside = (X <= BV) && (X >= -BV);
        float Yo = inside ? Y : X;
        float ldv = inside ? __logf(dydx) : 0.f;
        xst[sidx * 16 + slot] = (f16)Yo;
        ldb[sidx * 6 + dd] = ldv;
    }
}

// final layer (data net) + product + th staging + spline, per nt chunk
__device__ __forceinline__ void gemmFinN(const f16* __restrict__ ah, const f16* __restrict__ al,
                                         const float* __restrict__ bias,
                                         const f16* actW, f16* thW, f16* xst, float* ldb,
                                         const uint2 (&tcp)[9][4], int lane, int widS, int half){
    int l15 = lane & 15, g = lane >> 4, g4 = g * 4;
    float blv[9][4];
#pragma unroll
    for (int mt = 0; mt < 9; ++mt)
#pragma unroll
        for (int i = 0; i < 4; ++i){
            int f = mt * 16 + g4 + i;
            blv[mt][i] = bias[f < 138 ? f : 137];
        }
#pragma unroll 1
    for (int nt = 0; nt < 4; ++nt){
        f16x8 B0 = *actRd(actW, nt * 16 + l15, g * 16);
        f16x8 B1 = *actRd(actW, nt * 16 + l15, 64 + g * 16);
#pragma unroll
        for (int mt = 0; mt < 9; ++mt){
            f16x8 Ah0 = *(const f16x8*)(ah + ((mt * 2 + 0) * 64 + lane) * 8);
            f16x8 Ah1 = *(const f16x8*)(ah + ((mt * 2 + 1) * 64 + lane) * 8);
            f16x8 Al0 = *(const f16x8*)(al + ((mt * 2 + 0) * 64 + lane) * 8);
            f16x8 Al1 = *(const f16x8*)(al + ((mt * 2 + 1) * 64 + lane) * 8);
            f32x4 acc = {0.f, 0.f, 0.f, 0.f};
            acc = MF(Ah0, B0, acc);
            acc = MF(Al0, B0, acc);
            acc = MF(Ah1, B1, acc);
            acc = MF(Al1, B1, acc);
            float tc0 = unpl(tcp[mt][nt].x), tc1 = unph(tcp[mt][nt].x);
            float tc2 = unpl(tcp[mt][nt].y), tc3 = unph(tcp[mt][nt].y);
            float tv[4];
            tv[0] = leaky(acc[0] + blv[mt][0]) * tc0;
            tv[1] = leaky(acc[1] + blv[mt][1]) * tc1;
            tv[2] = leaky(acc[2] + blv[mt][2]) * tc2;
            tv[3] = leaky(acc[3] + blv[mt][3]) * tc3;
#pragma unroll
            for (int i = 0; i < 4; ++i){
                int f = mt * 16 + g4 + i;
                if (f < 138){
                    int dd = (f * 357) >> 13;
                    int p = f - dd * 23;
                    thW[l15 * 144 + dd * 24 + p] = (f16)tv[i];
                }
            }
        }
        spline_chunk(thW, xst, ldb, widS + nt * 16, half, lane);
    }
}

// ---------------- main kernel ----------------
extern "C" __global__ void __launch_bounds__(BLK, 2)
nsflow_main(const float* __restrict__ x_in, const float* __restrict__ xc_in,
            const float* __restrict__ convP, const float* __restrict__ convS,
            const float* __restrict__ convL, const float* __restrict__ convU,
            const float* __restrict__ n1b0, const float* __restrict__ n1bh, const float* __restrict__ n1bl,
            const float* __restrict__ n2b0, const float* __restrict__ n2bh, const float* __restrict__ n2bl,
            const float* __restrict__ c1b0, const float* __restrict__ c1bh, const float* __restrict__ c1bl,
            const float* __restrict__ c2b0, const float* __restrict__ c2bh, const float* __restrict__ c2bl,
            const f16* __restrict__ wsh, const f16* __restrict__ wsl,
            float* __restrict__ out){
    __shared__ float WcS[LLAYERS][DD][DD];
    __shared__ float ldcS;
    __shared__ f16 xcS[256 * 8];
    __shared__ f16 xstS[256 * 16];
    __shared__ float ldbS[256 * 6];
    __shared__ f16 actS[4 * 64 * 64];
    __shared__ f16 thS[4 * 16 * 144];

    // conv W = P (L+I) (U+diag(S)) and conv logdet
    for (int e = threadIdx.x; e < LLAYERS * DD * DD; e += BLK){
        int l = e / (DD * DD);
        int r = e - l * DD * DD;
        int i = r / DD;
        int j = r - i * DD;
        const float* P = convP + l * DD * DD;
        const float* Lm = convL + l * DD * DD;
        const float* Um = convU + l * DD * DD;
        const float* Sv = convS + l * DD;
        float acc = 0.f;
        for (int a = 0; a < DD; ++a){
            float inner = 0.f;
            for (int bb = 0; bb < DD; ++bb){
                float m1 = (bb < a) ? Lm[a * DD + bb] : (bb == a ? 1.f : 0.f);
                float m2 = (j > bb) ? Um[bb * DD + j] : (j == bb ? Sv[j] : 0.f);
                inner = fmaf(m1, m2, inner);
            }
            acc = fmaf(P[i * DD + a], inner, acc);
        }
        WcS[l][i][j] = acc;
    }
    if (threadIdx.x == 0){
        float sacc = 0.f;
        for (int q = 0; q < LLAYERS * DD; ++q) sacc += __logf(fabsf(convS[q]));
        ldcS = sacc;
    }

    int tid0 = threadIdx.x;
    int lane = tid0 & 63, wid = tid0 >> 6, widS = wid * 64;
    int gsamp = blockIdx.x * BLK + tid0;

    float xr[DD];
    {
        const float4* xv = (const float4*)(x_in + (size_t)gsamp * DD);
        float4 a0 = xv[0], a1 = xv[1], a2 = xv[2];
        xr[0]=a0.x; xr[1]=a0.y; xr[2]=a0.z; xr[3]=a0.w;
        xr[4]=a1.x; xr[5]=a1.y; xr[6]=a1.z; xr[7]=a1.w;
        xr[8]=a2.x; xr[9]=a2.y; xr[10]=a2.z; xr[11]=a2.w;
        float4 c0 = *(const float4*)(xc_in + (size_t)gsamp * 4);
        uint4 cv = { packh(c0.x, c0.y), packh(c0.z, c0.w), 0u, 0u };
        *(uint4*)(xcS + tid0 * 8) = cv;
    }
    __syncthreads();

    float logdet = ldcS;
    f16* actW = actS + wid * 4096;
    f16* thW = thS + wid * 2304;

#pragma unroll 1
    for (int l = 0; l < LLAYERS; ++l){
        if (l > 0){
            uint4 r0 = *(const uint4*)(xstS + tid0 * 16);
            uint4 r1 = *(const uint4*)(xstS + tid0 * 16 + 8);
            xr[0]=unpl(r0.x); xr[1]=unph(r0.x); xr[2]=unpl(r0.y); xr[3]=unph(r0.y);
            xr[4]=unpl(r0.z); xr[5]=unph(r0.z);
            xr[6]=unpl(r1.x); xr[7]=unph(r1.x); xr[8]=unpl(r1.y); xr[9]=unph(r1.y);
            xr[10]=unpl(r1.z); xr[11]=unph(r1.z);
        }
        // x = x @ Wconv[l]
        float xn[DD];
#pragma unroll
        for (int j = 0; j < DD; ++j) xn[j] = 0.f;
#pragma unroll
        for (int i = 0; i < DD; ++i){
            const float4* wr = (const float4*)WcS[l][i];
            float4 w0 = wr[0], w1 = wr[1], w2 = wr[2];
            float xi = xr[i];
            xn[0]=fmaf(xi,w0.x,xn[0]); xn[1]=fmaf(xi,w0.y,xn[1]); xn[2]=fmaf(xi,w0.z,xn[2]); xn[3]=fmaf(xi,w0.w,xn[3]);
            xn[4]=fmaf(xi,w1.x,xn[4]); xn[5]=fmaf(xi,w1.y,xn[5]); xn[6]=fmaf(xi,w1.z,xn[6]); xn[7]=fmaf(xi,w1.w,xn[7]);
            xn[8]=fmaf(xi,w2.x,xn[8]); xn[9]=fmaf(xi,w2.y,xn[9]); xn[10]=fmaf(xi,w2.z,xn[10]); xn[11]=fmaf(xi,w2.w,xn[11]);
        }
#pragma unroll
        for (int j = 0; j < DD; ++j) xr[j] = xn[j];
        // stage x (slots 0-5 = xr[0..5], 8-13 = xr[6..11])
        {
            uint4 s0 = { packh(xr[0],xr[1]), packh(xr[2],xr[3]), packh(xr[4],xr[5]), 0u };
            uint4 s1 = { packh(xr[6],xr[7]), packh(xr[8],xr[9]), packh(xr[10],xr[11]), 0u };
            *(uint4*)(xstS + tid0 * 16) = s0;
            *(uint4*)(xstS + tid0 * 16 + 8) = s1;
        }

#pragma unroll 1
        for (int half = 0; half < 2; ++half){
            const f16* whC = wsh + (size_t)(l * 4 + half * 2) * NLW;
            const f16* wlC = wsl + (size_t)(l * 4 + half * 2) * NLW;
            const f16* whN = whC + NLW;
            const f16* wlN = wlC + NLW;
            const float* b0c = (half ? c2b0 : c1b0) + l * 64;
            const float* bhc = (half ? c2bh : c1bh) + l * 128;
            const float* blc = (half ? c2bl : c1bl) + l * 138;
            const float* b0n = (half ? n2b0 : n1b0) + l * 64;
            const float* bhn = (half ? n2bh : n1bh) + l * 128;
            const float* bln = (half ? n2bl : n1bl) + l * 138;

            // conditioner chain
            gemmL0(whC, wlC, b0c, xcS, 8, 0, actW, lane, widS);
            gemm64(whC + WS_WH, wlC + WS_WH, bhc, actW, lane);
            gemm64(whC + WS_WH + 4096, wlC + WS_WH + 4096, bhc + 64, actW, lane);
            uint2 tcp[9][4];
            gemmFinC(whC + WS_WL, wlC + WS_WL, blc, actW, lane, tcp);

            // data chain (input = untouched half, from xstage)
            gemmL0(whN, wlN, b0n, xstS, 16, half * 8, actW, lane, widS);
            gemm64(whN + WS_WH, wlN + WS_WH, bhn, actW, lane);
            gemm64(whN + WS_WH + 4096, wlN + WS_WH + 4096, bhn + 64, actW, lane);
            gemmFinN(whN + WS_WL, wlN + WS_WL, bln, actW, thW, xstS, ldbS, tcp, lane, widS, half);

            // owner accumulates logdet
            float lsum = 0.f;
#pragma unroll
            for (int d = 0; d < 6; ++d) lsum += ldbS[tid0 * 6 + d];
            logdet += lsum;
        }
    }

    // final read-back and outputs
    {
        uint4 r0 = *(const uint4*)(xstS + tid0 * 16);
        uint4 r1 = *(const uint4*)(xstS + tid0 * 16 + 8);
        xr[0]=unpl(r0.x); xr[1]=unph(r0.x); xr[2]=unpl(r0.y); xr[3]=unph(r0.y);
        xr[4]=unpl(r0.z); xr[5]=unph(r0.z);
        xr[6]=unpl(r1.x); xr[7]=unph(r1.x); xr[8]=unpl(r1.y); xr[9]=unph(r1.y);
        xr[10]=unpl(r1.z); xr[11]=unph(r1.z);
    }
    float pr = 0.f;
#pragma unroll
    for (int j = 0; j < DD; ++j) pr = fmaf(-0.5f * xr[j], xr[j], pr);
    pr -= DD * 0.91893853320467274f;

    float4* ov = (float4*)(out + (size_t)gsamp * DD);
    ov[0] = make_float4(xr[0], xr[1], xr[2], xr[3]);
    ov[1] = make_float4(xr[4], xr[5], xr[6], xr[7]);
    ov[2] = make_float4(xr[8], xr[9], xr[10], xr[11]);
    out[(size_t)NSAMP * DD + gsamp] = logdet;
    out[(size_t)NSAMP * DD + NSAMP + gsamp] = pr;
}

extern "C" void kernel_launch(void* const* d_in, const int* in_sizes, int n_in,
                              void* d_out, int out_size, void* d_ws, size_t ws_size,
                              hipStream_t stream) {
    (void)in_sizes; (void)n_in; (void)out_size; (void)ws_size;
    const float* a[30];
    for (int i = 0; i < 30; ++i) a[i] = (const float*)d_in[i];
    f16* wsh = (f16*)d_ws;
    f16* wsl = wsh + 16 * NLW;   // needs 16*17920*2 f16 = 1,146,880 B of d_ws

    dim3 pg(70, 16);
    nsflow_prep<<<pg, 256, 0, stream>>>(a[6], a[8], a[10],      // net1 W0,Wh,Wl
                                        a[12], a[14], a[16],    // net2
                                        a[18], a[20], a[22],    // nc1
                                        a[24], a[26], a[28],    // nc2
                                        wsh, wsl);

    nsflow_main<<<NSAMP / BLK, BLK, 0, stream>>>(
        a[0], a[1], a[2], a[3], a[4], a[5],
        a[7], a[9], a[11],      // n1 b0,bh,bl
        a[13], a[15], a[17],    // n2
        a[19], a[21], a[23],    // c1
        a[25], a[27], a[29],    // c2
        wsh, wsl, (float*)d_out);
}